// Round 11
// baseline (2580.334 us; speedup 1.0000x reference)
//
#include <hip/hip_runtime.h>
#include <math.h>

#define BB   512
#define TT   256
#define HH   512
#define DIN  514
#define DOUTN 2
#define DT   0.1f
#define TH   (TT * HH)

typedef short s16x8 __attribute__((ext_vector_type(8)));
typedef float f32x4 __attribute__((ext_vector_type(4)));

__device__ __forceinline__ float retanh_f(float a) {
    float am = fminf(a, 15.0f);
    float E  = __expf(2.0f * am);
    float tp = __fdividef(E - 1.0f, E + 1.0f);
    return a > 0.0f ? tp : 0.0f;
}

__device__ __forceinline__ unsigned short f2bf(float f) {
    unsigned u = __float_as_uint(f);
    unsigned r = (u + 0x7FFFu + ((u >> 16) & 1u)) >> 16;
    return (unsigned short)r;
}

// ---------------------------------------------------------------------------
// Kernel 1a: WxT[d][j] = Wx[j][d]
// ---------------------------------------------------------------------------
__global__ __launch_bounds__(256) void transpose_wx(const float* __restrict__ Wx,
                                                    float* __restrict__ WxT) {
    int idx = blockIdx.x * 256 + threadIdx.x;
    if (idx < DIN * HH) {
        int d = idx / HH, j = idx % HH;
        WxT[idx] = Wx[j * DIN + d];
    }
}

// ---------------------------------------------------------------------------
// Kernel 1b: pack W_h into bf16 MFMA B-fragments (PROVEN rounds 6-10).
// frag f = (kc*32 + jt)*64 + lane, elem e: B[k][j]=Wh[j][k],
//   j = jt*16 + (lane&15), k = kc*32 + (lane>>4)*8 + e.
// ---------------------------------------------------------------------------
__global__ __launch_bounds__(256) void pack_wh(const float* __restrict__ Wh,
                                               unsigned short* __restrict__ Wp) {
    const int idx = blockIdx.x * 256 + threadIdx.x;   // 0..32767
    const int l  = idx & 63;
    const int jt = (idx >> 6) & 31;
    const int kc = idx >> 11;
    const int j  = jt * 16 + (l & 15);
    const int k0 = kc * 32 + (l >> 4) * 8;
    s16x8 pv;
    #pragma unroll
    for (int e = 0; e < 8; ++e) pv[e] = (short)f2bf(Wh[j * HH + k0 + e]);
    *(s16x8*)&Wp[(size_t)idx * 8] = pv;
}

// ---------------------------------------------------------------------------
// Kernel 2: x2ah = x @ WxT + b, packed with noise:
//   word = (bf16(x2) << 16) | bf16(noise). PROVEN rounds 9-10.
// ---------------------------------------------------------------------------
__global__ __launch_bounds__(256) void x2ah_kernel(const float* __restrict__ X,
                                                   const float* __restrict__ WxT,
                                                   const float* __restrict__ bias,
                                                   const float* __restrict__ noise,
                                                   unsigned int* __restrict__ outp) {
    __shared__ float xs[16][516];
    const int tid = threadIdx.x;
    const int r0  = blockIdx.x * 16;

    #pragma unroll
    for (int m = 0; m < 16; ++m) {
        const float* xr = X + (r0 + m) * DIN;
        xs[m][tid]       = xr[tid];
        xs[m][tid + 256] = xr[tid + 256];
        if (tid < 2) xs[m][512 + tid] = xr[512 + tid];
    }
    __syncthreads();

    const int j = 2 * tid;
    const float2 bv = *(const float2*)&bias[j];
    float acc[16][2];
    #pragma unroll
    for (int m = 0; m < 16; ++m) { acc[m][0] = bv.x; acc[m][1] = bv.y; }

    for (int d = 0; d < 512; d += 4) {
        const float2 w0 = *(const float2*)&WxT[(d + 0) * HH + j];
        const float2 w1 = *(const float2*)&WxT[(d + 1) * HH + j];
        const float2 w2 = *(const float2*)&WxT[(d + 2) * HH + j];
        const float2 w3 = *(const float2*)&WxT[(d + 3) * HH + j];
        #pragma unroll
        for (int m = 0; m < 16; ++m) {
            const float4 xv = *(const float4*)&xs[m][d];
            acc[m][0] += xv.x * w0.x; acc[m][1] += xv.x * w0.y;
            acc[m][0] += xv.y * w1.x; acc[m][1] += xv.y * w1.y;
            acc[m][0] += xv.z * w2.x; acc[m][1] += xv.z * w2.y;
            acc[m][0] += xv.w * w3.x; acc[m][1] += xv.w * w3.y;
        }
    }
    {
        const float2 wa = *(const float2*)&WxT[512 * HH + j];
        const float2 wb = *(const float2*)&WxT[513 * HH + j];
        #pragma unroll
        for (int m = 0; m < 16; ++m) {
            acc[m][0] += xs[m][512] * wa.x; acc[m][1] += xs[m][512] * wa.y;
            acc[m][0] += xs[m][513] * wb.x; acc[m][1] += xs[m][513] * wb.y;
        }
    }
    #pragma unroll
    for (int m = 0; m < 16; ++m) {
        const float2 nv = *(const float2*)&noise[(r0 + m) * HH + j];
        unsigned int p0 = ((unsigned)f2bf(acc[m][0]) << 16) | f2bf(nv.x);
        unsigned int p1 = ((unsigned)f2bf(acc[m][1]) << 16) | f2bf(nv.y);
        *(uint2*)&outp[(r0 + m) * HH + j] = make_uint2(p0, p1);
    }
}

// ---------------------------------------------------------------------------
// Kernel 3 (Design H5): MFMA scan, W resident, 256-thr WG / 512-reg waves.
// 32 WGs x 256 thr (4 waves, 1 wave/SIMD), __launch_bounds__(256,1).
//   kc 0..3  : LDS (128 KB)
//   kc 4..11 : 64 AGPR-pinned frags (256 AGPR = the accum cap)
//   kc 12..13: 16 VGPR-pinned frags (64 arch regs)
//   kc 14..15: streamed from L2 via one 8-frag buffer (64 KB/WG/step)
// Arch demand ~212 <= 256, total ~468 <= 512 -> real slack, no spills.
// Wave w owns j-tiles 8w..8w+7. h stores reuse dead pk regs, deferred past
// barrier 2. Fragment maps bit-identical to proven rounds 6-10.
// ---------------------------------------------------------------------------
#define WDECL8(KC) \
    s16x8 wr##KC##_0, wr##KC##_1, wr##KC##_2, wr##KC##_3, \
          wr##KC##_4, wr##KC##_5, wr##KC##_6, wr##KC##_7

#define WLOAD8(KC) do { \
    wr##KC##_0 = WpL[(KC) * 2048 + w8 + 0 * 64]; \
    wr##KC##_1 = WpL[(KC) * 2048 + w8 + 1 * 64]; \
    wr##KC##_2 = WpL[(KC) * 2048 + w8 + 2 * 64]; \
    wr##KC##_3 = WpL[(KC) * 2048 + w8 + 3 * 64]; \
    wr##KC##_4 = WpL[(KC) * 2048 + w8 + 4 * 64]; \
    wr##KC##_5 = WpL[(KC) * 2048 + w8 + 5 * 64]; \
    wr##KC##_6 = WpL[(KC) * 2048 + w8 + 6 * 64]; \
    wr##KC##_7 = WpL[(KC) * 2048 + w8 + 7 * 64]; \
} while (0)

#define WPIN8A(KC) asm volatile("" : \
    "+a"(wr##KC##_0), "+a"(wr##KC##_1), "+a"(wr##KC##_2), "+a"(wr##KC##_3), \
    "+a"(wr##KC##_4), "+a"(wr##KC##_5), "+a"(wr##KC##_6), "+a"(wr##KC##_7))

#define WPIN8V(KC) asm volatile("" : \
    "+v"(wr##KC##_0), "+v"(wr##KC##_1), "+v"(wr##KC##_2), "+v"(wr##KC##_3), \
    "+v"(wr##KC##_4), "+v"(wr##KC##_5), "+v"(wr##KC##_6), "+v"(wr##KC##_7))

#define MFMA8(A, B0, B1, B2, B3, B4, B5, B6, B7) do { \
    acc0 = __builtin_amdgcn_mfma_f32_16x16x32_bf16(A, B0, acc0, 0, 0, 0); \
    acc1 = __builtin_amdgcn_mfma_f32_16x16x32_bf16(A, B1, acc1, 0, 0, 0); \
    acc2 = __builtin_amdgcn_mfma_f32_16x16x32_bf16(A, B2, acc2, 0, 0, 0); \
    acc3 = __builtin_amdgcn_mfma_f32_16x16x32_bf16(A, B3, acc3, 0, 0, 0); \
    acc4 = __builtin_amdgcn_mfma_f32_16x16x32_bf16(A, B4, acc4, 0, 0, 0); \
    acc5 = __builtin_amdgcn_mfma_f32_16x16x32_bf16(A, B5, acc5, 0, 0, 0); \
    acc6 = __builtin_amdgcn_mfma_f32_16x16x32_bf16(A, B6, acc6, 0, 0, 0); \
    acc7 = __builtin_amdgcn_mfma_f32_16x16x32_bf16(A, B7, acc7, 0, 0, 0); \
} while (0)

#define KSTEP_R(KC) do { \
    const s16x8 A = *(const s16x8*)&hrow[(KC) * 32]; \
    MFMA8(A, wr##KC##_0, wr##KC##_1, wr##KC##_2, wr##KC##_3, \
             wr##KC##_4, wr##KC##_5, wr##KC##_6, wr##KC##_7); \
} while (0)

#define KSTEP_L(KC) do { \
    const s16x8 A  = *(const s16x8*)&hrow[(KC) * 32]; \
    const s16x8 B0 = WlL[(KC) * 2048 + w8 + 0 * 64]; \
    const s16x8 B1 = WlL[(KC) * 2048 + w8 + 1 * 64]; \
    const s16x8 B2 = WlL[(KC) * 2048 + w8 + 2 * 64]; \
    const s16x8 B3 = WlL[(KC) * 2048 + w8 + 3 * 64]; \
    const s16x8 B4 = WlL[(KC) * 2048 + w8 + 4 * 64]; \
    const s16x8 B5 = WlL[(KC) * 2048 + w8 + 5 * 64]; \
    const s16x8 B6 = WlL[(KC) * 2048 + w8 + 6 * 64]; \
    const s16x8 B7 = WlL[(KC) * 2048 + w8 + 7 * 64]; \
    MFMA8(A, B0, B1, B2, B3, B4, B5, B6, B7); \
} while (0)

#define SLOADST(KC) do { \
    st0 = WpL[(KC) * 2048 + w8 + 0 * 64]; \
    st1 = WpL[(KC) * 2048 + w8 + 1 * 64]; \
    st2 = WpL[(KC) * 2048 + w8 + 2 * 64]; \
    st3 = WpL[(KC) * 2048 + w8 + 3 * 64]; \
    st4 = WpL[(KC) * 2048 + w8 + 4 * 64]; \
    st5 = WpL[(KC) * 2048 + w8 + 5 * 64]; \
    st6 = WpL[(KC) * 2048 + w8 + 6 * 64]; \
    st7 = WpL[(KC) * 2048 + w8 + 7 * 64]; \
} while (0)

#define KSTEP_ST(KC) do { \
    const s16x8 A = *(const s16x8*)&hrow[(KC) * 32]; \
    MFMA8(A, st0, st1, st2, st3, st4, st5, st6, st7); \
} while (0)

#define PKL(N) do { \
    pk##N##_0 = hio[gb + 0 * TH + jn##N]; \
    pk##N##_1 = hio[gb + 1 * TH + jn##N]; \
    pk##N##_2 = hio[gb + 2 * TH + jn##N]; \
    pk##N##_3 = hio[gb + 3 * TH + jn##N]; \
} while (0)

// consumes pk, overwrites pk with h bits (register reuse), updates hs
#define EPI1(N, R) do { \
    const unsigned int p = pk##N##_##R; \
    const float x2 = __uint_as_float(p & 0xffff0000u); \
    const float nz = __uint_as_float(p << 16); \
    float a = ahv##N[R]; \
    a += DT * (acc##N[R] + x2 - a); \
    ahv##N[R] = a; \
    const float h = retanh_f(a) + nz; \
    pk##N##_##R = __float_as_uint(h); \
    hs[lg4 + (R)][jn##N] = f2bf(h); \
} while (0)

#define EPI(N) do { EPI1(N, 0); EPI1(N, 1); EPI1(N, 2); EPI1(N, 3); } while (0)

#define STOREH(N) do { \
    hio[gb + 0 * TH + jn##N] = pk##N##_0; \
    hio[gb + 1 * TH + jn##N] = pk##N##_1; \
    hio[gb + 2 * TH + jn##N] = pk##N##_2; \
    hio[gb + 3 * TH + jn##N] = pk##N##_3; \
} while (0)

__global__ __launch_bounds__(256, 1) void scan11_kernel(const unsigned short* __restrict__ Wp,
                                                        const float* __restrict__ ah0,
                                                        unsigned int* __restrict__ hio) {
    __shared__ __align__(16) unsigned short Wl[4 * 32 * 64 * 8];  // 128 KB: kc 0..3
    __shared__ __align__(16) unsigned short hs[16][520];          // 16.25 KB

    const int tid = threadIdx.x;
    const int l   = tid & 63;
    const int w   = tid >> 6;        // wave 0..3 -> j-tiles 8w..8w+7
    const int w8  = w << 9;          // 8*w*64
    const int lm  = l & 15;
    const int lg  = l >> 4;
    const int lg4 = lg * 4;
    const int b0  = blockIdx.x * 16;

    const s16x8* WpV = (const s16x8*)Wp;
    s16x8* WlV = (s16x8*)Wl;

    // one-time: kc 0..3 into LDS
    for (int idx = tid; idx < 4 * 32 * 64; idx += 256)
        WlV[idx] = WpV[idx];

    const s16x8* WpL = WpV + l;

    // one-time: kc 4..11 into 64 AGPR-pinned frags (256 AGPR)
    WDECL8(4); WDECL8(5); WDECL8(6); WDECL8(7);
    WDECL8(8); WDECL8(9); WDECL8(10); WDECL8(11);
    WLOAD8(4); WLOAD8(5); WLOAD8(6); WLOAD8(7);
    WLOAD8(8); WLOAD8(9); WLOAD8(10); WLOAD8(11);
    WPIN8A(4); WPIN8A(5); WPIN8A(6); WPIN8A(7);
    WPIN8A(8); WPIN8A(9); WPIN8A(10); WPIN8A(11);

    // one-time: kc 12..13 into 16 VGPR-pinned frags (64 arch regs)
    WDECL8(12); WDECL8(13);
    WLOAD8(12); WLOAD8(13);
    WPIN8V(12); WPIN8V(13);

    const int jn0 = ((w << 3) + 0) * 16 + lm;
    const int jn1 = ((w << 3) + 1) * 16 + lm;
    const int jn2 = ((w << 3) + 2) * 16 + lm;
    const int jn3 = ((w << 3) + 3) * 16 + lm;
    const int jn4 = ((w << 3) + 4) * 16 + lm;
    const int jn5 = ((w << 3) + 5) * 16 + lm;
    const int jn6 = ((w << 3) + 6) * 16 + lm;
    const int jn7 = ((w << 3) + 7) * 16 + lm;

    f32x4 ahv0, ahv1, ahv2, ahv3, ahv4, ahv5, ahv6, ahv7;
    {
        const float a0 = ah0[jn0], a1 = ah0[jn1], a2 = ah0[jn2], a3 = ah0[jn3];
        const float a4 = ah0[jn4], a5 = ah0[jn5], a6 = ah0[jn6], a7 = ah0[jn7];
        ahv0 = (f32x4){a0, a0, a0, a0};  ahv1 = (f32x4){a1, a1, a1, a1};
        ahv2 = (f32x4){a2, a2, a2, a2};  ahv3 = (f32x4){a3, a3, a3, a3};
        ahv4 = (f32x4){a4, a4, a4, a4};  ahv5 = (f32x4){a5, a5, a5, a5};
        ahv6 = (f32x4){a6, a6, a6, a6};  ahv7 = (f32x4){a7, a7, a7, a7};
    }

    // init h(t=0) = retanh(ah0), same for all batch rows
    for (int idx = tid; idx < 16 * 512; idx += 256) {
        int b = idx >> 9, k = idx & 511;
        hs[b][k] = f2bf(retanh_f(ah0[k]));
    }
    __syncthreads();

    const unsigned short* hrow = &hs[lm][lg * 8];
    const s16x8* WlL = WlV + l;

    int gb = (b0 + lg4) * TH;   // + t*HH added incrementally

    for (int t = 0; t < TT; ++t) {
        // stream kc14 first (L2), then packed x2|noise (HBM)
        s16x8 st0, st1, st2, st3, st4, st5, st6, st7;
        SLOADST(14);

        unsigned int pk0_0, pk0_1, pk0_2, pk0_3;
        unsigned int pk1_0, pk1_1, pk1_2, pk1_3;
        unsigned int pk2_0, pk2_1, pk2_2, pk2_3;
        unsigned int pk3_0, pk3_1, pk3_2, pk3_3;
        unsigned int pk4_0, pk4_1, pk4_2, pk4_3;
        unsigned int pk5_0, pk5_1, pk5_2, pk5_3;
        unsigned int pk6_0, pk6_1, pk6_2, pk6_3;
        unsigned int pk7_0, pk7_1, pk7_2, pk7_3;
        PKL(0); PKL(1); PKL(2); PKL(3);
        PKL(4); PKL(5); PKL(6); PKL(7);

        f32x4 acc0 = (f32x4){0.f, 0.f, 0.f, 0.f};
        f32x4 acc1 = (f32x4){0.f, 0.f, 0.f, 0.f};
        f32x4 acc2 = (f32x4){0.f, 0.f, 0.f, 0.f};
        f32x4 acc3 = (f32x4){0.f, 0.f, 0.f, 0.f};
        f32x4 acc4 = (f32x4){0.f, 0.f, 0.f, 0.f};
        f32x4 acc5 = (f32x4){0.f, 0.f, 0.f, 0.f};
        f32x4 acc6 = (f32x4){0.f, 0.f, 0.f, 0.f};
        f32x4 acc7 = (f32x4){0.f, 0.f, 0.f, 0.f};

        // LDS kcs while stream kc14 lands
        KSTEP_L(0); KSTEP_L(1); KSTEP_L(2); KSTEP_L(3);
        // consume stream kc14, reissue for kc15
        KSTEP_ST(14);
        SLOADST(15);
        // resident kcs (zero memory traffic)
        KSTEP_R(4); KSTEP_R(5); KSTEP_R(6); KSTEP_R(7);
        KSTEP_R(8); KSTEP_R(9); KSTEP_R(10); KSTEP_R(11);
        KSTEP_R(12); KSTEP_R(13);
        // consume stream kc15
        KSTEP_ST(15);

        __syncthreads();   // barrier 1: all reads of hs(t) complete

        EPI(0); EPI(1); EPI(2); EPI(3);
        EPI(4); EPI(5); EPI(6); EPI(7);

        __syncthreads();   // barrier 2: hs(t+1) complete (LDS-only drain)

        // deferred global h stores (pk regs now hold h bits)
        STOREH(0); STOREH(1); STOREH(2); STOREH(3);
        STOREH(4); STOREH(5); STOREH(6); STOREH(7);
        gb += HH;
    }
}

// ---------------------------------------------------------------------------
// Kernel 4: tiny output projection (reads fp32 h written by the scan)
// ---------------------------------------------------------------------------
__global__ __launch_bounds__(256) void out_kernel(const float* __restrict__ hstore,
                                                  const float* __restrict__ Wy,
                                                  float* __restrict__ out0) {
    const int wave = threadIdx.x >> 6;
    const int lane = threadIdx.x & 63;
    const int r = blockIdx.x * 4 + wave;

    const float4* hv4 = (const float4*)&hstore[r * HH];
    float a0 = 0.0f, a1 = 0.0f;
    #pragma unroll
    for (int u = 0; u < 2; ++u) {
        const int e = u * 64 + lane;
        const float4 h  = hv4[e];
        const float4 w0 = *(const float4*)&Wy[e * 4];
        const float4 w1 = *(const float4*)&Wy[HH + e * 4];
        a0 += h.x * w0.x + h.y * w0.y + h.z * w0.z + h.w * w0.w;
        a1 += h.x * w1.x + h.y * w1.y + h.z * w1.z + h.w * w1.w;
    }
    #pragma unroll
    for (int off = 32; off > 0; off >>= 1) {
        a0 += __shfl_xor(a0, off);
        a1 += __shfl_xor(a1, off);
    }
    if (lane == 0) {
        out0[r * 2]     = a0;
        out0[r * 2 + 1] = a1;
    }
}

// ---------------------------------------------------------------------------
extern "C" void kernel_launch(void* const* d_in, const int* in_sizes, int n_in,
                              void* d_out, int out_size, void* d_ws, size_t ws_size,
                              hipStream_t stream) {
    const float* x     = (const float*)d_in[0];  // [B,T,DIN]
    const float* noise = (const float*)d_in[1];  // [B,T,H]
    const float* Wx    = (const float*)d_in[2];  // [H,DIN]
    const float* bah   = (const float*)d_in[3];  // [H]
    const float* Wh    = (const float*)d_in[4];  // [H,H]
    const float* Wy    = (const float*)d_in[5];  // [DOUT,H]
    const float* ah0   = (const float*)d_in[6];  // [H]

    float* out0   = (float*)d_out;                   // [B,T,DOUT]
    float* hstore = (float*)d_out + BB * TT * DOUTN; // [B,T,H]

    float* WxT = (float*)d_ws;                              // [DIN,H] fp32
    unsigned short* Wp = (unsigned short*)(WxT + DIN * HH); // [512*512] bf16

    transpose_wx<<<(DIN * HH + 255) / 256, 256, 0, stream>>>(Wx, WxT);
    pack_wh<<<16 * 32 * 64 / 256, 256, 0, stream>>>(Wh, Wp);
    x2ah_kernel<<<BB * TT / 16, 256, 0, stream>>>(x, WxT, bah, noise,
                                                  (unsigned int*)hstore);
    scan11_kernel<<<BB / 16, 256, 0, stream>>>(Wp, ah0, (unsigned int*)hstore);
    out_kernel<<<BB * TT / 4, 256, 0, stream>>>(hstore, Wy, out0);
}

// Round 12
// 1874.965 us; speedup vs baseline: 1.3762x; 1.3762x over previous
//
#include <hip/hip_runtime.h>
#include <math.h>

#define BB   512
#define TT   256
#define HH   512
#define DIN  514
#define DOUTN 2
#define DT   0.1f
#define TH   (TT * HH)

#define NSL   4      // j-slices per group (128 cols each)
#define NGRP  32     // batch groups (16 batches each)

typedef short s16x8 __attribute__((ext_vector_type(8)));
typedef float f32x4 __attribute__((ext_vector_type(4)));

__device__ __forceinline__ float retanh_f(float a) {
    float am = fminf(a, 15.0f);
    float E  = __expf(2.0f * am);
    float tp = __fdividef(E - 1.0f, E + 1.0f);
    return a > 0.0f ? tp : 0.0f;
}

__device__ __forceinline__ unsigned short f2bf(float f) {
    unsigned u = __float_as_uint(f);
    unsigned r = (u + 0x7FFFu + ((u >> 16) & 1u)) >> 16;
    return (unsigned short)r;
}

// ---------------------------------------------------------------------------
// Kernel 1a: WxT[d][j] = Wx[j][d]
// ---------------------------------------------------------------------------
__global__ __launch_bounds__(256) void transpose_wx(const float* __restrict__ Wx,
                                                    float* __restrict__ WxT) {
    int idx = blockIdx.x * 256 + threadIdx.x;
    if (idx < DIN * HH) {
        int d = idx / HH, j = idx % HH;
        WxT[idx] = Wx[j * DIN + d];
    }
}

// ---------------------------------------------------------------------------
// Kernel 1b: pack W_h into bf16 MFMA B-fragments (PROVEN rounds 6-11).
// frag f = (kc*32 + jt)*64 + lane, elem e: B[k][j]=Wh[j][k],
//   j = jt*16 + (lane&15), k = kc*32 + (lane>>4)*8 + e.
// ---------------------------------------------------------------------------
__global__ __launch_bounds__(256) void pack_wh(const float* __restrict__ Wh,
                                               unsigned short* __restrict__ Wp) {
    const int idx = blockIdx.x * 256 + threadIdx.x;   // 0..32767
    const int l  = idx & 63;
    const int jt = (idx >> 6) & 31;
    const int kc = idx >> 11;
    const int j  = jt * 16 + (l & 15);
    const int k0 = kc * 32 + (l >> 4) * 8;
    s16x8 pv;
    #pragma unroll
    for (int e = 0; e < 8; ++e) pv[e] = (short)f2bf(Wh[j * HH + k0 + e]);
    *(s16x8*)&Wp[(size_t)idx * 8] = pv;
}

// ---------------------------------------------------------------------------
// Kernel 2: x2ah = x @ WxT + b, packed with noise (PROVEN rounds 9-11):
//   word = (bf16(x2) << 16) | bf16(noise)
// ---------------------------------------------------------------------------
__global__ __launch_bounds__(256) void x2ah_kernel(const float* __restrict__ X,
                                                   const float* __restrict__ WxT,
                                                   const float* __restrict__ bias,
                                                   const float* __restrict__ noise,
                                                   unsigned int* __restrict__ outp) {
    __shared__ float xs[16][516];
    const int tid = threadIdx.x;
    const int r0  = blockIdx.x * 16;

    #pragma unroll
    for (int m = 0; m < 16; ++m) {
        const float* xr = X + (r0 + m) * DIN;
        xs[m][tid]       = xr[tid];
        xs[m][tid + 256] = xr[tid + 256];
        if (tid < 2) xs[m][512 + tid] = xr[512 + tid];
    }
    __syncthreads();

    const int j = 2 * tid;
    const float2 bv = *(const float2*)&bias[j];
    float acc[16][2];
    #pragma unroll
    for (int m = 0; m < 16; ++m) { acc[m][0] = bv.x; acc[m][1] = bv.y; }

    for (int d = 0; d < 512; d += 4) {
        const float2 w0 = *(const float2*)&WxT[(d + 0) * HH + j];
        const float2 w1 = *(const float2*)&WxT[(d + 1) * HH + j];
        const float2 w2 = *(const float2*)&WxT[(d + 2) * HH + j];
        const float2 w3 = *(const float2*)&WxT[(d + 3) * HH + j];
        #pragma unroll
        for (int m = 0; m < 16; ++m) {
            const float4 xv = *(const float4*)&xs[m][d];
            acc[m][0] += xv.x * w0.x; acc[m][1] += xv.x * w0.y;
            acc[m][0] += xv.y * w1.x; acc[m][1] += xv.y * w1.y;
            acc[m][0] += xv.z * w2.x; acc[m][1] += xv.z * w2.y;
            acc[m][0] += xv.w * w3.x; acc[m][1] += xv.w * w3.y;
        }
    }
    {
        const float2 wa = *(const float2*)&WxT[512 * HH + j];
        const float2 wb = *(const float2*)&WxT[513 * HH + j];
        #pragma unroll
        for (int m = 0; m < 16; ++m) {
            acc[m][0] += xs[m][512] * wa.x; acc[m][1] += xs[m][512] * wa.y;
            acc[m][0] += xs[m][513] * wb.x; acc[m][1] += xs[m][513] * wb.y;
        }
    }
    #pragma unroll
    for (int m = 0; m < 16; ++m) {
        const float2 nv = *(const float2*)&noise[(r0 + m) * HH + j];
        unsigned int p0 = ((unsigned)f2bf(acc[m][0]) << 16) | f2bf(nv.x);
        unsigned int p1 = ((unsigned)f2bf(acc[m][1]) << 16) | f2bf(nv.y);
        *(uint2*)&outp[(r0 + m) * HH + j] = make_uint2(p0, p1);
    }
}

// ---------------------------------------------------------------------------
// Kernel 3 (Design J): j-sliced MFMA scan with LLC h-exchange.
// 128 WGs x 512 thr cooperative: gid = g*NSL + s; group g = batches 16g..16g+15,
// slice s = j-cols 128s..128s+127. Wave w owns j-tile (8s+w): its W share is
// 16 frags = 64 VGPRs (resident, pinned, demand ~120 << 256).
// Per step: 16 MFMA + 16 A b128-reads; epilogue; publish own 4KB bf16 h-slice
// (coalesced u64 agent stores from LDS); per-wave vmcnt(0) drain; barrier;
// flag; poll 4 flags; gather group's 16KB h from LLC into hs. NO fences,
// NO sc0, NO placement assumptions — round-4-proven sync machinery only.
// Inbox [2][512][512] bf16, parity by t; flags [TT][NGRP][NSL] memset once.
// ---------------------------------------------------------------------------
#define WKLOAD(KC) s16x8 wk##KC = WpV[((KC) * 32 + s * 8 + w) * 64 + l]
#define WKPIN(A, B, C, D) asm volatile("" : "+v"(A), "+v"(B), "+v"(C), "+v"(D))

#define KC_EVEN(KC) do { \
    const s16x8 A = *(const s16x8*)&hrow[(KC) * 32]; \
    accA = __builtin_amdgcn_mfma_f32_16x16x32_bf16(A, wk##KC, accA, 0, 0, 0); \
} while (0)
#define KC_ODD(KC) do { \
    const s16x8 A = *(const s16x8*)&hrow[(KC) * 32]; \
    accB = __builtin_amdgcn_mfma_f32_16x16x32_bf16(A, wk##KC, accB, 0, 0, 0); \
} while (0)

__global__ __launch_bounds__(512) void scan12_kernel(const unsigned short* __restrict__ Wp,
                                                     const float* __restrict__ ah0,
                                                     unsigned int* __restrict__ hio,
                                                     unsigned short* inbox,
                                                     unsigned int* flags) {
    __shared__ __align__(16) unsigned short hs[16][520];   // h state, all 512 j

    const int tid = threadIdx.x;
    const int l   = tid & 63;
    const int w   = tid >> 6;          // wave 0..7
    const int lm  = l & 15;
    const int lg  = l >> 4;
    const int lg4 = lg * 4;
    const int gid = blockIdx.x;
    const int g   = gid >> 2;          // group 0..31
    const int s   = gid & 3;           // slice 0..3
    const int b0  = g * 16;

    const s16x8* WpV = (const s16x8*)Wp;

    // one-time: this wave's 16 W fragments (64 VGPRs)
    WKLOAD(0);  WKLOAD(1);  WKLOAD(2);  WKLOAD(3);
    WKLOAD(4);  WKLOAD(5);  WKLOAD(6);  WKLOAD(7);
    WKLOAD(8);  WKLOAD(9);  WKLOAD(10); WKLOAD(11);
    WKLOAD(12); WKLOAD(13); WKLOAD(14); WKLOAD(15);
    WKPIN(wk0, wk1, wk2, wk3);     WKPIN(wk4, wk5, wk6, wk7);
    WKPIN(wk8, wk9, wk10, wk11);   WKPIN(wk12, wk13, wk14, wk15);

    const int jn = (s * 8 + w) * 16 + lm;   // this lane's j column

    f32x4 ahv;
    {
        const float a0 = ah0[jn];
        ahv = (f32x4){a0, a0, a0, a0};
    }

    // init h(t=0) = retanh(ah0), same for all batch rows
    for (int idx = tid; idx < 16 * 512; idx += 512) {
        int b = idx >> 9, k = idx & 511;
        hs[b][k] = f2bf(retanh_f(ah0[k]));
    }
    __syncthreads();

    const unsigned short* hrow = &hs[lm][lg * 8];

    // publish/gather thread mapping
    const int pb = tid >> 5;            // batch row 0..15
    const int pq = tid & 31;            // 0..31
    unsigned long long* ibx = (unsigned long long*)inbox;
    const int pubIdx = (((b0 + pb) << 9) + s * 128 + pq * 4) >> 2;  // u64 index
    const int gatIdx = (((b0 + pb) << 9) + pq * 16) >> 2;

    int gb = (b0 + lg4) * TH + jn;      // + t*HH added incrementally

    for (int t = 0; t < TT; ++t) {
        const int par = (t & 1) << 16;  // parity offset in u64 units (65536)

        // packed x2|noise loads for this step (consumed in epilogue)
        const unsigned int pk0 = hio[gb + 0 * TH];
        const unsigned int pk1 = hio[gb + 1 * TH];
        const unsigned int pk2 = hio[gb + 2 * TH];
        const unsigned int pk3 = hio[gb + 3 * TH];

        // ---- GEMM: acc = hs(t-1) @ W[:, jtile], two interleaved chains ----
        f32x4 accA = (f32x4){0.f, 0.f, 0.f, 0.f};
        f32x4 accB = (f32x4){0.f, 0.f, 0.f, 0.f};
        KC_EVEN(0);  KC_ODD(1);  KC_EVEN(2);  KC_ODD(3);
        KC_EVEN(4);  KC_ODD(5);  KC_EVEN(6);  KC_ODD(7);
        KC_EVEN(8);  KC_ODD(9);  KC_EVEN(10); KC_ODD(11);
        KC_EVEN(12); KC_ODD(13); KC_EVEN(14); KC_ODD(15);
        const f32x4 acc = accA + accB;

        __syncthreads();   // BAR1: all hs(t-1) reads complete

        // ---- epilogue: 4 batch rows; write fp32 h to hio, bf16 h to hs ----
        {
            float a, h;
            unsigned int p;
            p = pk0; a = ahv[0];
            a += DT * (acc[0] + __uint_as_float(p & 0xffff0000u) - a);
            ahv[0] = a; h = retanh_f(a) + __uint_as_float(p << 16);
            hio[gb + 0 * TH] = __float_as_uint(h); hs[lg4 + 0][jn] = f2bf(h);
            p = pk1; a = ahv[1];
            a += DT * (acc[1] + __uint_as_float(p & 0xffff0000u) - a);
            ahv[1] = a; h = retanh_f(a) + __uint_as_float(p << 16);
            hio[gb + 1 * TH] = __float_as_uint(h); hs[lg4 + 1][jn] = f2bf(h);
            p = pk2; a = ahv[2];
            a += DT * (acc[2] + __uint_as_float(p & 0xffff0000u) - a);
            ahv[2] = a; h = retanh_f(a) + __uint_as_float(p << 16);
            hio[gb + 2 * TH] = __float_as_uint(h); hs[lg4 + 2][jn] = f2bf(h);
            p = pk3; a = ahv[3];
            a += DT * (acc[3] + __uint_as_float(p & 0xffff0000u) - a);
            ahv[3] = a; h = retanh_f(a) + __uint_as_float(p << 16);
            hio[gb + 3 * TH] = __float_as_uint(h); hs[lg4 + 3][jn] = f2bf(h);
        }

        __syncthreads();   // BAR2: own hs slice complete

        // ---- publish own slice (4 KB) coalesced from LDS to inbox (LLC) ----
        {
            const unsigned long long pub =
                *(const unsigned long long*)&hs[pb][s * 128 + pq * 4];
            __hip_atomic_store(&ibx[par + pubIdx], pub, __ATOMIC_RELAXED,
                               __HIP_MEMORY_SCOPE_AGENT);
        }
        asm volatile("s_waitcnt vmcnt(0)" ::: "memory");
        __syncthreads();   // BAR3: all waves' publishes drained

        unsigned int* fl = flags + (t * NGRP + g) * NSL;
        if (tid == 0)
            __hip_atomic_store(&fl[s], 1u, __ATOMIC_RELAXED, __HIP_MEMORY_SCOPE_AGENT);
        if (tid < NSL) {
            while (__hip_atomic_load(&fl[tid], __ATOMIC_RELAXED,
                                     __HIP_MEMORY_SCOPE_AGENT) == 0u)
                __builtin_amdgcn_s_sleep(1);
        }
        __syncthreads();   // BAR4: flags seen by all

        // ---- gather group's full h(t) (16 KB) from inbox into hs ----
        {
            const unsigned long long g0 = __hip_atomic_load(&ibx[par + gatIdx + 0],
                __ATOMIC_RELAXED, __HIP_MEMORY_SCOPE_AGENT);
            const unsigned long long g1 = __hip_atomic_load(&ibx[par + gatIdx + 1],
                __ATOMIC_RELAXED, __HIP_MEMORY_SCOPE_AGENT);
            const unsigned long long g2 = __hip_atomic_load(&ibx[par + gatIdx + 2],
                __ATOMIC_RELAXED, __HIP_MEMORY_SCOPE_AGENT);
            const unsigned long long g3 = __hip_atomic_load(&ibx[par + gatIdx + 3],
                __ATOMIC_RELAXED, __HIP_MEMORY_SCOPE_AGENT);
            *(unsigned long long*)&hs[pb][pq * 16 + 0]  = g0;
            *(unsigned long long*)&hs[pb][pq * 16 + 4]  = g1;
            *(unsigned long long*)&hs[pb][pq * 16 + 8]  = g2;
            *(unsigned long long*)&hs[pb][pq * 16 + 12] = g3;
        }
        __syncthreads();   // BAR5: hs(t) complete for next step

        gb += HH;
    }
}

// ---------------------------------------------------------------------------
// Kernel 4: tiny output projection (reads fp32 h written by the scan)
// ---------------------------------------------------------------------------
__global__ __launch_bounds__(256) void out_kernel(const float* __restrict__ hstore,
                                                  const float* __restrict__ Wy,
                                                  float* __restrict__ out0) {
    const int wave = threadIdx.x >> 6;
    const int lane = threadIdx.x & 63;
    const int r = blockIdx.x * 4 + wave;

    const float4* hv4 = (const float4*)&hstore[r * HH];
    float a0 = 0.0f, a1 = 0.0f;
    #pragma unroll
    for (int u = 0; u < 2; ++u) {
        const int e = u * 64 + lane;
        const float4 h  = hv4[e];
        const float4 w0 = *(const float4*)&Wy[e * 4];
        const float4 w1 = *(const float4*)&Wy[HH + e * 4];
        a0 += h.x * w0.x + h.y * w0.y + h.z * w0.z + h.w * w0.w;
        a1 += h.x * w1.x + h.y * w1.y + h.z * w1.z + h.w * w1.w;
    }
    #pragma unroll
    for (int off = 32; off > 0; off >>= 1) {
        a0 += __shfl_xor(a0, off);
        a1 += __shfl_xor(a1, off);
    }
    if (lane == 0) {
        out0[r * 2]     = a0;
        out0[r * 2 + 1] = a1;
    }
}

// ---------------------------------------------------------------------------
extern "C" void kernel_launch(void* const* d_in, const int* in_sizes, int n_in,
                              void* d_out, int out_size, void* d_ws, size_t ws_size,
                              hipStream_t stream) {
    const float* x     = (const float*)d_in[0];  // [B,T,DIN]
    const float* noise = (const float*)d_in[1];  // [B,T,H]
    const float* Wx    = (const float*)d_in[2];  // [H,DIN]
    const float* bah   = (const float*)d_in[3];  // [H]
    const float* Wh    = (const float*)d_in[4];  // [H,H]
    const float* Wy    = (const float*)d_in[5];  // [DOUT,H]
    const float* ah0   = (const float*)d_in[6];  // [H]

    float* out0   = (float*)d_out;                   // [B,T,DOUT]
    float* hstore = (float*)d_out + BB * TT * DOUTN; // [B,T,H]

    float* WxT = (float*)d_ws;                                  // 1.054 MB
    unsigned short* Wp    = (unsigned short*)(WxT + DIN * HH);  // 512 KB
    unsigned short* inbox = Wp + HH * HH;                       // 1 MB (2 parities)
    unsigned int*   flags = (unsigned int*)(inbox + 2 * BB * HH); // 128 KB

    transpose_wx<<<(DIN * HH + 255) / 256, 256, 0, stream>>>(Wx, WxT);
    pack_wh<<<16 * 32 * 64 / 256, 256, 0, stream>>>(Wh, Wp);
    x2ah_kernel<<<BB * TT / 16, 256, 0, stream>>>(x, WxT, bah, noise,
                                                  (unsigned int*)hstore);

    hipMemsetAsync(flags, 0, (size_t)TT * NGRP * NSL * sizeof(unsigned int), stream);
    {
        const unsigned short* wpp = Wp;
        unsigned int* hiop = (unsigned int*)hstore;
        unsigned short* ibp = inbox;
        unsigned int* flp = flags;
        void* args[] = { (void*)&wpp, (void*)&ah0, (void*)&hiop,
                         (void*)&ibp, (void*)&flp };
        hipLaunchCooperativeKernel((void*)scan12_kernel, dim3(NGRP * NSL),
                                   dim3(512), args, 0, stream);
    }

    out_kernel<<<BB * TT / 4, 256, 0, stream>>>(hstore, Wy, out0);
}

// Round 13
// 1377.707 us; speedup vs baseline: 1.8729x; 1.3609x over previous
//
#include <hip/hip_runtime.h>
#include <math.h>

#define BB   512
#define TT   256
#define HH   512
#define DIN  514
#define DOUTN 2
#define DT   0.1f
#define TH   (TT * HH)

#define NSL   4      // scan: j-slices per group
#define NGRP  32     // scan: batch groups

typedef short s16x8 __attribute__((ext_vector_type(8)));
typedef float f32x4 __attribute__((ext_vector_type(4)));

__device__ __forceinline__ float retanh_f(float a) {
    float am = fminf(a, 15.0f);
    float E  = __expf(2.0f * am);
    float tp = __fdividef(E - 1.0f, E + 1.0f);
    return a > 0.0f ? tp : 0.0f;
}

__device__ __forceinline__ unsigned short f2bf(float f) {
    unsigned u = __float_as_uint(f);
    unsigned r = (u + 0x7FFFu + ((u >> 16) & 1u)) >> 16;
    return (unsigned short)r;
}

// ---------------------------------------------------------------------------
// Kernel 1a: pack W_h into bf16 MFMA B-fragments (PROVEN rounds 6-12).
// frag f = (kc*32 + jt)*64 + lane, elem e: B[k][j]=Wh[j][k],
//   j = jt*16 + (lane&15), k = kc*32 + (lane>>4)*8 + e.
// ---------------------------------------------------------------------------
__global__ __launch_bounds__(256) void pack_wh(const float* __restrict__ Wh,
                                               unsigned short* __restrict__ Wp) {
    const int idx = blockIdx.x * 256 + threadIdx.x;   // 0..32767
    const int l  = idx & 63;
    const int jt = (idx >> 6) & 31;
    const int kc = idx >> 11;
    const int j  = jt * 16 + (l & 15);
    const int k0 = kc * 32 + (l >> 4) * 8;
    s16x8 pv;
    #pragma unroll
    for (int e = 0; e < 8; ++e) pv[e] = (short)f2bf(Wh[j * HH + k0 + e]);
    *(s16x8*)&Wp[(size_t)idx * 8] = pv;
}

// ---------------------------------------------------------------------------
// Kernel 1b: pack W_x (k=0..511) into bf16 hi/lo MFMA B-fragments,
// same fragment map as pack_wh. Tail k=512,513 handled in-GEMM via fp32.
// ---------------------------------------------------------------------------
__global__ __launch_bounds__(256) void pack_wx(const float* __restrict__ Wx,
                                               unsigned short* __restrict__ WfH,
                                               unsigned short* __restrict__ WfL) {
    const int idx = blockIdx.x * 256 + threadIdx.x;   // 0..32767
    const int l  = idx & 63;
    const int jt = (idx >> 6) & 31;
    const int kc = idx >> 11;
    const int j  = jt * 16 + (l & 15);
    const int k0 = kc * 32 + (l >> 4) * 8;
    s16x8 ph, pl;
    #pragma unroll
    for (int e = 0; e < 8; ++e) {
        const float v = Wx[(size_t)j * DIN + k0 + e];
        const unsigned short hi = f2bf(v);
        const float hv = __uint_as_float((unsigned)hi << 16);
        ph[e] = (short)hi;
        pl[e] = (short)f2bf(v - hv);
    }
    *(s16x8*)&WfH[(size_t)idx * 8] = ph;
    *(s16x8*)&WfL[(size_t)idx * 8] = pl;
}

// ---------------------------------------------------------------------------
// Kernel 2 (NEW): x2ah via MFMA with bf16 hi/lo compensation.
// 2048 WGs x 512 thr; WG = 64 rows x 512 cols. Per kc (16):
//   stage x-slice [64][32] as hi/lo bf16 (LDS) + W kc-block (64 KB, frag order)
//   wave w: rt=w&3 (16 rows), j-half=(w>>2) (16 j-tiles); 3 MFMA per (jt):
//   hi*hi + lo*hi + hi*lo  (error ~2^-17 ~ fp32-grade)
// Tail k=512,513: exact fp32 VALU. Epilogue: C bounced through LDS (aliases
// dead W buffer) in 4 row-chunks -> coalesced noise read + packed u32 store:
//   word = (bf16(x2) << 16) | bf16(noise)   (same format as rounds 9-12)
// ---------------------------------------------------------------------------
__global__ __launch_bounds__(512) void x2ah_mfma(const float* __restrict__ X,
                                                 const unsigned short* __restrict__ WfH,
                                                 const unsigned short* __restrict__ WfL,
                                                 const float* __restrict__ Wx,
                                                 const float* __restrict__ bias,
                                                 const float* __restrict__ noise,
                                                 unsigned int* __restrict__ outp) {
    __shared__ __align__(16) char arena[5120 + 5120 + 512 + 65536];
    unsigned short* xh = (unsigned short*)arena;            // [64][40]
    unsigned short* xl = xh + 64 * 40;                      // [64][40]
    float*          xt = (float*)(xl + 64 * 40);            // [64][2]
    s16x8*         wsh = (s16x8*)(xt + 128);                // 2048 frags (32 KB)
    s16x8*         wsl = wsh + 2048;                        // 2048 frags (32 KB)
    unsigned short* ls = (unsigned short*)wsh;              // epilogue alias [16][512]

    const int tid = threadIdx.x;
    const int l   = tid & 63;
    const int w   = tid >> 6;
    const int lm  = l & 15;
    const int lg  = l >> 4;
    const int lg4 = lg * 4;
    const int r0  = blockIdx.x * 64;

    const int rt  = w & 3;
    const int jt0 = (w >> 2) * 16;

    // one-time: fp32 tail columns of x
    if (tid < 128) {
        const int row = tid >> 1, c2 = tid & 1;
        xt[row * 2 + c2] = X[(size_t)(r0 + row) * DIN + 512 + c2];
    }

    f32x4 acc[16];
    #pragma unroll
    for (int jt = 0; jt < 16; ++jt) acc[jt] = (f32x4){0.f, 0.f, 0.f, 0.f};

    const s16x8* WfHv = (const s16x8*)WfH;
    const s16x8* WfLv = (const s16x8*)WfL;

    for (int kc = 0; kc < 16; ++kc) {
        // ---- stage x-slice [64 rows][32 k] as hi/lo ----
        {
            const int row = tid >> 3, q = tid & 7;
            const float* xp = X + (size_t)(r0 + row) * DIN + kc * 32 + q * 4;
            const float2 v0 = *(const float2*)xp;
            const float2 v1 = *(const float2*)(xp + 2);
            float vv[4] = {v0.x, v0.y, v1.x, v1.y};
            ushort4 hh, llv;
            unsigned short* hp = (unsigned short*)&hh;
            unsigned short* lp = (unsigned short*)&llv;
            #pragma unroll
            for (int e = 0; e < 4; ++e) {
                const unsigned short hi = f2bf(vv[e]);
                hp[e] = hi;
                lp[e] = f2bf(vv[e] - __uint_as_float((unsigned)hi << 16));
            }
            *(ushort4*)&xh[row * 40 + q * 4] = hh;
            *(ushort4*)&xl[row * 40 + q * 4] = llv;
        }
        // ---- stage W kc-block (frag order, straight copy) ----
        {
            const size_t base = (size_t)kc * 2048 + tid * 4;
            wsh[tid * 4 + 0] = WfHv[base + 0];
            wsh[tid * 4 + 1] = WfHv[base + 1];
            wsh[tid * 4 + 2] = WfHv[base + 2];
            wsh[tid * 4 + 3] = WfHv[base + 3];
            wsl[tid * 4 + 0] = WfLv[base + 0];
            wsl[tid * 4 + 1] = WfLv[base + 1];
            wsl[tid * 4 + 2] = WfLv[base + 2];
            wsl[tid * 4 + 3] = WfLv[base + 3];
        }
        __syncthreads();

        const s16x8 Ah = *(const s16x8*)&xh[(rt * 16 + lm) * 40 + lg * 8];
        const s16x8 Al = *(const s16x8*)&xl[(rt * 16 + lm) * 40 + lg * 8];
        #pragma unroll
        for (int jt = 0; jt < 16; ++jt) {
            const s16x8 Bh = wsh[(jt0 + jt) * 64 + l];
            const s16x8 Bl = wsl[(jt0 + jt) * 64 + l];
            acc[jt] = __builtin_amdgcn_mfma_f32_16x16x32_bf16(Ah, Bh, acc[jt], 0, 0, 0);
            acc[jt] = __builtin_amdgcn_mfma_f32_16x16x32_bf16(Al, Bh, acc[jt], 0, 0, 0);
            acc[jt] = __builtin_amdgcn_mfma_f32_16x16x32_bf16(Ah, Bl, acc[jt], 0, 0, 0);
        }
        __syncthreads();
    }

    // ---- epilogue: 4 row-chunks of 16, bounced through LDS (aliases W) ----
    for (int c = 0; c < 4; ++c) {
        if (rt == c) {
            #pragma unroll
            for (int jt = 0; jt < 16; ++jt) {
                const int j = (jt0 + jt) * 16 + lm;
                const float2 wt = *(const float2*)&Wx[(size_t)j * DIN + 512];
                const float bj = bias[j];
                #pragma unroll
                for (int r = 0; r < 4; ++r) {
                    const int rl = lg4 + r;   // local row 0..15
                    const float v = acc[jt][r] + bj
                                  + xt[(c * 16 + rl) * 2 + 0] * wt.x
                                  + xt[(c * 16 + rl) * 2 + 1] * wt.y;
                    ls[rl * 512 + j] = f2bf(v);
                }
            }
        }
        __syncthreads();
        {
            const int i   = tid * 16;
            const int row = i >> 9, col = i & 511;
            const size_t gi = (size_t)(r0 + c * 16 + row) * HH + col;
            const float4 n0 = *(const float4*)&noise[gi + 0];
            const float4 n1 = *(const float4*)&noise[gi + 4];
            const float4 n2 = *(const float4*)&noise[gi + 8];
            const float4 n3 = *(const float4*)&noise[gi + 12];
            const unsigned short* lp = &ls[row * 512 + col];
            const uint4 la = *(const uint4*)lp;         // bf16 pairs 0..7
            const uint4 lb = *(const uint4*)(lp + 8);   // bf16 pairs 8..15
            uint4 o0, o1, o2, o3;
            o0.x = ((la.x & 0xffffu) << 16) | f2bf(n0.x);
            o0.y = (la.x & 0xffff0000u)     | f2bf(n0.y);
            o0.z = ((la.y & 0xffffu) << 16) | f2bf(n0.z);
            o0.w = (la.y & 0xffff0000u)     | f2bf(n0.w);
            o1.x = ((la.z & 0xffffu) << 16) | f2bf(n1.x);
            o1.y = (la.z & 0xffff0000u)     | f2bf(n1.y);
            o1.z = ((la.w & 0xffffu) << 16) | f2bf(n1.z);
            o1.w = (la.w & 0xffff0000u)     | f2bf(n1.w);
            o2.x = ((lb.x & 0xffffu) << 16) | f2bf(n2.x);
            o2.y = (lb.x & 0xffff0000u)     | f2bf(n2.y);
            o2.z = ((lb.y & 0xffffu) << 16) | f2bf(n2.z);
            o2.w = (lb.y & 0xffff0000u)     | f2bf(n2.w);
            o3.x = ((lb.z & 0xffffu) << 16) | f2bf(n3.x);
            o3.y = (lb.z & 0xffff0000u)     | f2bf(n3.y);
            o3.z = ((lb.w & 0xffffu) << 16) | f2bf(n3.z);
            o3.w = (lb.w & 0xffff0000u)     | f2bf(n3.w);
            *(uint4*)&outp[gi + 0]  = o0;
            *(uint4*)&outp[gi + 4]  = o1;
            *(uint4*)&outp[gi + 8]  = o2;
            *(uint4*)&outp[gi + 12] = o3;
        }
        __syncthreads();
    }
}

// ---------------------------------------------------------------------------
// Kernel 3 (Design J, PROVEN round 12): j-sliced MFMA scan, LLC h-exchange.
// ---------------------------------------------------------------------------
#define WKLOAD(KC) s16x8 wk##KC = WpV[((KC) * 32 + s * 8 + w) * 64 + l]
#define WKPIN(A, B, C, D) asm volatile("" : "+v"(A), "+v"(B), "+v"(C), "+v"(D))

#define KC_EVEN(KC) do { \
    const s16x8 A = *(const s16x8*)&hrow[(KC) * 32]; \
    accA = __builtin_amdgcn_mfma_f32_16x16x32_bf16(A, wk##KC, accA, 0, 0, 0); \
} while (0)
#define KC_ODD(KC) do { \
    const s16x8 A = *(const s16x8*)&hrow[(KC) * 32]; \
    accB = __builtin_amdgcn_mfma_f32_16x16x32_bf16(A, wk##KC, accB, 0, 0, 0); \
} while (0)

__global__ __launch_bounds__(512) void scan12_kernel(const unsigned short* __restrict__ Wp,
                                                     const float* __restrict__ ah0,
                                                     unsigned int* __restrict__ hio,
                                                     unsigned short* inbox,
                                                     unsigned int* flags) {
    __shared__ __align__(16) unsigned short hs[16][520];

    const int tid = threadIdx.x;
    const int l   = tid & 63;
    const int w   = tid >> 6;
    const int lm  = l & 15;
    const int lg  = l >> 4;
    const int lg4 = lg * 4;
    const int gid = blockIdx.x;
    const int g   = gid >> 2;
    const int s   = gid & 3;
    const int b0  = g * 16;

    const s16x8* WpV = (const s16x8*)Wp;

    WKLOAD(0);  WKLOAD(1);  WKLOAD(2);  WKLOAD(3);
    WKLOAD(4);  WKLOAD(5);  WKLOAD(6);  WKLOAD(7);
    WKLOAD(8);  WKLOAD(9);  WKLOAD(10); WKLOAD(11);
    WKLOAD(12); WKLOAD(13); WKLOAD(14); WKLOAD(15);
    WKPIN(wk0, wk1, wk2, wk3);     WKPIN(wk4, wk5, wk6, wk7);
    WKPIN(wk8, wk9, wk10, wk11);   WKPIN(wk12, wk13, wk14, wk15);

    const int jn = (s * 8 + w) * 16 + lm;

    f32x4 ahv;
    {
        const float a0 = ah0[jn];
        ahv = (f32x4){a0, a0, a0, a0};
    }

    for (int idx = tid; idx < 16 * 512; idx += 512) {
        int b = idx >> 9, k = idx & 511;
        hs[b][k] = f2bf(retanh_f(ah0[k]));
    }
    __syncthreads();

    const unsigned short* hrow = &hs[lm][lg * 8];

    const int pb = tid >> 5;
    const int pq = tid & 31;
    unsigned long long* ibx = (unsigned long long*)inbox;
    const int pubIdx = (((b0 + pb) << 9) + s * 128 + pq * 4) >> 2;
    const int gatIdx = (((b0 + pb) << 9) + pq * 16) >> 2;

    int gb = (b0 + lg4) * TH + jn;

    for (int t = 0; t < TT; ++t) {
        const int par = (t & 1) << 16;

        const unsigned int pk0 = hio[gb + 0 * TH];
        const unsigned int pk1 = hio[gb + 1 * TH];
        const unsigned int pk2 = hio[gb + 2 * TH];
        const unsigned int pk3 = hio[gb + 3 * TH];

        f32x4 accA = (f32x4){0.f, 0.f, 0.f, 0.f};
        f32x4 accB = (f32x4){0.f, 0.f, 0.f, 0.f};
        KC_EVEN(0);  KC_ODD(1);  KC_EVEN(2);  KC_ODD(3);
        KC_EVEN(4);  KC_ODD(5);  KC_EVEN(6);  KC_ODD(7);
        KC_EVEN(8);  KC_ODD(9);  KC_EVEN(10); KC_ODD(11);
        KC_EVEN(12); KC_ODD(13); KC_EVEN(14); KC_ODD(15);
        const f32x4 acc = accA + accB;

        __syncthreads();

        {
            float a, h;
            unsigned int p;
            p = pk0; a = ahv[0];
            a += DT * (acc[0] + __uint_as_float(p & 0xffff0000u) - a);
            ahv[0] = a; h = retanh_f(a) + __uint_as_float(p << 16);
            hio[gb + 0 * TH] = __float_as_uint(h); hs[lg4 + 0][jn] = f2bf(h);
            p = pk1; a = ahv[1];
            a += DT * (acc[1] + __uint_as_float(p & 0xffff0000u) - a);
            ahv[1] = a; h = retanh_f(a) + __uint_as_float(p << 16);
            hio[gb + 1 * TH] = __float_as_uint(h); hs[lg4 + 1][jn] = f2bf(h);
            p = pk2; a = ahv[2];
            a += DT * (acc[2] + __uint_as_float(p & 0xffff0000u) - a);
            ahv[2] = a; h = retanh_f(a) + __uint_as_float(p << 16);
            hio[gb + 2 * TH] = __float_as_uint(h); hs[lg4 + 2][jn] = f2bf(h);
            p = pk3; a = ahv[3];
            a += DT * (acc[3] + __uint_as_float(p & 0xffff0000u) - a);
            ahv[3] = a; h = retanh_f(a) + __uint_as_float(p << 16);
            hio[gb + 3 * TH] = __float_as_uint(h); hs[lg4 + 3][jn] = f2bf(h);
        }

        __syncthreads();

        {
            const unsigned long long pub =
                *(const unsigned long long*)&hs[pb][s * 128 + pq * 4];
            __hip_atomic_store(&ibx[par + pubIdx], pub, __ATOMIC_RELAXED,
                               __HIP_MEMORY_SCOPE_AGENT);
        }
        asm volatile("s_waitcnt vmcnt(0)" ::: "memory");
        __syncthreads();

        unsigned int* fl = flags + (t * NGRP + g) * NSL;
        if (tid == 0)
            __hip_atomic_store(&fl[s], 1u, __ATOMIC_RELAXED, __HIP_MEMORY_SCOPE_AGENT);
        if (tid < NSL) {
            while (__hip_atomic_load(&fl[tid], __ATOMIC_RELAXED,
                                     __HIP_MEMORY_SCOPE_AGENT) == 0u)
                __builtin_amdgcn_s_sleep(1);
        }
        __syncthreads();

        {
            const unsigned long long g0 = __hip_atomic_load(&ibx[par + gatIdx + 0],
                __ATOMIC_RELAXED, __HIP_MEMORY_SCOPE_AGENT);
            const unsigned long long g1 = __hip_atomic_load(&ibx[par + gatIdx + 1],
                __ATOMIC_RELAXED, __HIP_MEMORY_SCOPE_AGENT);
            const unsigned long long g2 = __hip_atomic_load(&ibx[par + gatIdx + 2],
                __ATOMIC_RELAXED, __HIP_MEMORY_SCOPE_AGENT);
            const unsigned long long g3 = __hip_atomic_load(&ibx[par + gatIdx + 3],
                __ATOMIC_RELAXED, __HIP_MEMORY_SCOPE_AGENT);
            *(unsigned long long*)&hs[pb][pq * 16 + 0]  = g0;
            *(unsigned long long*)&hs[pb][pq * 16 + 4]  = g1;
            *(unsigned long long*)&hs[pb][pq * 16 + 8]  = g2;
            *(unsigned long long*)&hs[pb][pq * 16 + 12] = g3;
        }
        __syncthreads();

        gb += HH;
    }
}

// ---------------------------------------------------------------------------
// Kernel 4: tiny output projection (reads fp32 h written by the scan)
// ---------------------------------------------------------------------------
__global__ __launch_bounds__(256) void out_kernel(const float* __restrict__ hstore,
                                                  const float* __restrict__ Wy,
                                                  float* __restrict__ out0) {
    const int wave = threadIdx.x >> 6;
    const int lane = threadIdx.x & 63;
    const int r = blockIdx.x * 4 + wave;

    const float4* hv4 = (const float4*)&hstore[r * HH];
    float a0 = 0.0f, a1 = 0.0f;
    #pragma unroll
    for (int u = 0; u < 2; ++u) {
        const int e = u * 64 + lane;
        const float4 h  = hv4[e];
        const float4 w0 = *(const float4*)&Wy[e * 4];
        const float4 w1 = *(const float4*)&Wy[HH + e * 4];
        a0 += h.x * w0.x + h.y * w0.y + h.z * w0.z + h.w * w0.w;
        a1 += h.x * w1.x + h.y * w1.y + h.z * w1.z + h.w * w1.w;
    }
    #pragma unroll
    for (int off = 32; off > 0; off >>= 1) {
        a0 += __shfl_xor(a0, off);
        a1 += __shfl_xor(a1, off);
    }
    if (lane == 0) {
        out0[r * 2]     = a0;
        out0[r * 2 + 1] = a1;
    }
}

// ---------------------------------------------------------------------------
extern "C" void kernel_launch(void* const* d_in, const int* in_sizes, int n_in,
                              void* d_out, int out_size, void* d_ws, size_t ws_size,
                              hipStream_t stream) {
    const float* x     = (const float*)d_in[0];  // [B,T,DIN]
    const float* noise = (const float*)d_in[1];  // [B,T,H]
    const float* Wx    = (const float*)d_in[2];  // [H,DIN]
    const float* bah   = (const float*)d_in[3];  // [H]
    const float* Wh    = (const float*)d_in[4];  // [H,H]
    const float* Wy    = (const float*)d_in[5];  // [DOUT,H]
    const float* ah0   = (const float*)d_in[6];  // [H]

    float* out0   = (float*)d_out;                   // [B,T,DOUT]
    float* hstore = (float*)d_out + BB * TT * DOUTN; // [B,T,H]

    const size_t FRAG_U16 = (size_t)16 * 32 * 64 * 8;      // 262144 u16 = 512 KB
    unsigned short* Wp    = (unsigned short*)d_ws;          // scan Wh frags
    unsigned short* WxH   = Wp + FRAG_U16;                  // x2ah Wx hi frags
    unsigned short* WxL   = WxH + FRAG_U16;                 // x2ah Wx lo frags
    unsigned short* inbox = WxL + FRAG_U16;                 // 1 MB (2 parities)
    unsigned int*   flags = (unsigned int*)(inbox + 2 * BB * HH);  // 128 KB

    pack_wh<<<16 * 32 * 64 / 256, 256, 0, stream>>>(Wh, Wp);
    pack_wx<<<16 * 32 * 64 / 256, 256, 0, stream>>>(Wx, WxH, WxL);
    x2ah_mfma<<<BB * TT / 64, 512, 0, stream>>>(x, WxH, WxL, Wx, bah, noise,
                                                (unsigned int*)hstore);

    hipMemsetAsync(flags, 0, (size_t)TT * NGRP * NSL * sizeof(unsigned int), stream);
    {
        const unsigned short* wpp = Wp;
        unsigned int* hiop = (unsigned int*)hstore;
        unsigned short* ibp = inbox;
        unsigned int* flp = flags;
        void* args[] = { (void*)&wpp, (void*)&ah0, (void*)&hiop,
                         (void*)&ibp, (void*)&flp };
        hipLaunchCooperativeKernel((void*)scan12_kernel, dim3(NGRP * NSL),
                                   dim3(512), args, 0, stream);
    }

    out_kernel<<<BB * TT / 4, 256, 0, stream>>>(hstore, Wy, out0);
}

// Round 14
// 1119.102 us; speedup vs baseline: 2.3057x; 1.2311x over previous
//
#include <hip/hip_runtime.h>
#include <math.h>

#define BB   512
#define TT   256
#define HH   512
#define DIN  514
#define DOUTN 2
#define DT   0.1f
#define TH   (TT * HH)

#define NSL   4      // scan: j-slices per group
#define NGRP  32     // scan: batch groups

typedef short s16x8 __attribute__((ext_vector_type(8)));
typedef float f32x4 __attribute__((ext_vector_type(4)));

__device__ __forceinline__ float retanh_f(float a) {
    float am = fminf(a, 15.0f);
    float E  = __expf(2.0f * am);
    float tp = __fdividef(E - 1.0f, E + 1.0f);
    return a > 0.0f ? tp : 0.0f;
}

__device__ __forceinline__ unsigned short f2bf(float f) {
    unsigned u = __float_as_uint(f);
    unsigned r = (u + 0x7FFFu + ((u >> 16) & 1u)) >> 16;
    return (unsigned short)r;
}

// async global->LDS, 16B per lane; LDS dest = wave-uniform base + lane*16
__device__ __forceinline__ void gload_lds16(const void* g, void* l) {
    __builtin_amdgcn_global_load_lds(
        (const __attribute__((address_space(1))) unsigned int*)g,
        (__attribute__((address_space(3))) unsigned int*)l, 16, 0, 0);
}

// ---------------------------------------------------------------------------
// Kernel 1a: pack W_h into bf16 MFMA B-fragments (PROVEN rounds 6-13).
// ---------------------------------------------------------------------------
__global__ __launch_bounds__(256) void pack_wh(const float* __restrict__ Wh,
                                               unsigned short* __restrict__ Wp) {
    const int idx = blockIdx.x * 256 + threadIdx.x;   // 0..32767
    const int l  = idx & 63;
    const int jt = (idx >> 6) & 31;
    const int kc = idx >> 11;
    const int j  = jt * 16 + (l & 15);
    const int k0 = kc * 32 + (l >> 4) * 8;
    s16x8 pv;
    #pragma unroll
    for (int e = 0; e < 8; ++e) pv[e] = (short)f2bf(Wh[j * HH + k0 + e]);
    *(s16x8*)&Wp[(size_t)idx * 8] = pv;
}

// ---------------------------------------------------------------------------
// Kernel 1b: pack W_x (k<512) into bf16 hi/lo fragments (PROVEN round 13).
// ---------------------------------------------------------------------------
__global__ __launch_bounds__(256) void pack_wx(const float* __restrict__ Wx,
                                               unsigned short* __restrict__ WfH,
                                               unsigned short* __restrict__ WfL) {
    const int idx = blockIdx.x * 256 + threadIdx.x;   // 0..32767
    const int l  = idx & 63;
    const int jt = (idx >> 6) & 31;
    const int kc = idx >> 11;
    const int j  = jt * 16 + (l & 15);
    const int k0 = kc * 32 + (l >> 4) * 8;
    s16x8 ph, pl;
    #pragma unroll
    for (int e = 0; e < 8; ++e) {
        const float v = Wx[(size_t)j * DIN + k0 + e];
        const unsigned short hi = f2bf(v);
        const float hv = __uint_as_float((unsigned)hi << 16);
        ph[e] = (short)hi;
        pl[e] = (short)f2bf(v - hv);
    }
    *(s16x8*)&WfH[(size_t)idx * 8] = ph;
    *(s16x8*)&WfL[(size_t)idx * 8] = pl;
}

// ---------------------------------------------------------------------------
// Kernel 2 (v2): x2ah via MFMA hi/lo. 1024 WGs x 512 thr; WG = 128 rows.
//   W: double-buffered LDS (2x64KB) via async global_load_lds (stage kc+1
//      during compute kc; the end-of-iter barrier drains it).
//   x: per-lane registers (raw float4 prefetch 1 kc ahead; convert at top).
//   Wave w: rows rt*32..rt*32+31 (2 A-frags), j-tiles jt0..jt0+15.
//   Math identical to proven round 13: hi*hi + lo*hi + hi*lo, fp32 tail,
//   epilogue bounced through LDS alias, packed (bf16(x2)<<16)|bf16(noise).
// ---------------------------------------------------------------------------
__device__ __forceinline__ void cvt_hilo(float4 a, float4 b, s16x8& hi, s16x8& lo) {
    float v[8] = {a.x, a.y, a.z, a.w, b.x, b.y, b.z, b.w};
    #pragma unroll
    for (int e = 0; e < 8; ++e) {
        const unsigned short h = f2bf(v[e]);
        hi[e] = (short)h;
        lo[e] = (short)f2bf(v[e] - __uint_as_float((unsigned)h << 16));
    }
}

#define STAGE_W(KC, DST) do { \
    const s16x8* gh = WfHv + (size_t)(KC) * 2048 + w * 256 + l; \
    const s16x8* gl = WfLv + (size_t)(KC) * 2048 + w * 256 + l; \
    s16x8* dh = (DST) + w * 256; \
    s16x8* dl = (DST) + 2048 + w * 256; \
    gload_lds16(gh + 0 * 64, dh + 0 * 64); \
    gload_lds16(gh + 1 * 64, dh + 1 * 64); \
    gload_lds16(gh + 2 * 64, dh + 2 * 64); \
    gload_lds16(gh + 3 * 64, dh + 3 * 64); \
    gload_lds16(gl + 0 * 64, dl + 0 * 64); \
    gload_lds16(gl + 1 * 64, dl + 1 * 64); \
    gload_lds16(gl + 2 * 64, dl + 2 * 64); \
    gload_lds16(gl + 3 * 64, dl + 3 * 64); \
} while (0)

__global__ __launch_bounds__(512) void x2ah_mfma(const float* __restrict__ X,
                                                 const unsigned short* __restrict__ WfH,
                                                 const unsigned short* __restrict__ WfL,
                                                 const float* __restrict__ Wx,
                                                 const float* __restrict__ bias,
                                                 const float* __restrict__ noise,
                                                 unsigned int* __restrict__ outp) {
    __shared__ __align__(16) char arena[2][65536];   // [buf][hi 32KB | lo 32KB]

    const int tid = threadIdx.x;
    const int l   = tid & 63;
    const int w   = tid >> 6;
    const int lm  = l & 15;
    const int lg  = l >> 4;
    const int lg4 = lg * 4;
    const int lg8 = lg * 8;
    const int r0  = blockIdx.x * 128;

    const int rt  = w & 3;             // row block: rows rt*32 .. rt*32+31
    const int jt0 = (w >> 2) * 16;

    const s16x8* WfHv = (const s16x8*)WfH;
    const s16x8* WfLv = (const s16x8*)WfL;

    const float* xr0 = X + (size_t)(r0 + rt * 32 + lm) * DIN;
    const float* xr1 = xr0 + 16 * DIN;

    // prologue: x raw prefetch (kc=0) + stage W kc=0 into buf0
    float4 xa0 = *(const float4*)(xr0 + lg8);
    float4 xb0 = *(const float4*)(xr0 + lg8 + 4);
    float4 xa1 = *(const float4*)(xr1 + lg8);
    float4 xb1 = *(const float4*)(xr1 + lg8 + 4);
    STAGE_W(0, (s16x8*)arena[0]);
    __syncthreads();

    f32x4 acc0[16], acc1[16];
    #pragma unroll
    for (int jt = 0; jt < 16; ++jt) {
        acc0[jt] = (f32x4){0.f, 0.f, 0.f, 0.f};
        acc1[jt] = (f32x4){0.f, 0.f, 0.f, 0.f};
    }

    for (int kc = 0; kc < 16; ++kc) {
        s16x8* cur = (s16x8*)arena[kc & 1];
        s16x8* nxt = (s16x8*)arena[(kc & 1) ^ 1];
        if (kc < 15) STAGE_W(kc + 1, nxt);   // async; drained by end barrier

        s16x8 Ah0, Al0, Ah1, Al1;
        cvt_hilo(xa0, xb0, Ah0, Al0);
        cvt_hilo(xa1, xb1, Ah1, Al1);
        if (kc < 15) {
            const int off = (kc + 1) * 32 + lg8;
            xa0 = *(const float4*)(xr0 + off);
            xb0 = *(const float4*)(xr0 + off + 4);
            xa1 = *(const float4*)(xr1 + off);
            xb1 = *(const float4*)(xr1 + off + 4);
        }

        #pragma unroll
        for (int jt = 0; jt < 16; ++jt) {
            const s16x8 Bh = cur[(jt0 + jt) * 64 + l];
            const s16x8 Bl = cur[2048 + (jt0 + jt) * 64 + l];
            acc0[jt] = __builtin_amdgcn_mfma_f32_16x16x32_bf16(Ah0, Bh, acc0[jt], 0, 0, 0);
            acc0[jt] = __builtin_amdgcn_mfma_f32_16x16x32_bf16(Al0, Bh, acc0[jt], 0, 0, 0);
            acc0[jt] = __builtin_amdgcn_mfma_f32_16x16x32_bf16(Ah0, Bl, acc0[jt], 0, 0, 0);
            acc1[jt] = __builtin_amdgcn_mfma_f32_16x16x32_bf16(Ah1, Bh, acc1[jt], 0, 0, 0);
            acc1[jt] = __builtin_amdgcn_mfma_f32_16x16x32_bf16(Al1, Bh, acc1[jt], 0, 0, 0);
            acc1[jt] = __builtin_amdgcn_mfma_f32_16x16x32_bf16(Ah1, Bl, acc1[jt], 0, 0, 0);
        }
        __syncthreads();
    }

    // epilogue: 8 chunks of 16 rows, bounced through LDS alias
    unsigned short* ls = (unsigned short*)arena;   // [16][512]
    for (int c = 0; c < 8; ++c) {
        if (rt == (c >> 1)) {
            float xt0[4], xt1[4];
            #pragma unroll
            for (int r = 0; r < 4; ++r) {
                const float* xrow = X + (size_t)(r0 + c * 16 + lg4 + r) * DIN + 512;
                xt0[r] = xrow[0];
                xt1[r] = xrow[1];
            }
            #pragma unroll
            for (int jt = 0; jt < 16; ++jt) {
                const int j = (jt0 + jt) * 16 + lm;
                const float2 wt = *(const float2*)&Wx[(size_t)j * DIN + 512];
                const float bj = bias[j];
                #pragma unroll
                for (int r = 0; r < 4; ++r) {
                    const float av = (c & 1) ? acc1[jt][r] : acc0[jt][r];
                    const float v = av + bj + xt0[r] * wt.x + xt1[r] * wt.y;
                    ls[(lg4 + r) * 512 + j] = f2bf(v);
                }
            }
        }
        __syncthreads();
        {
            const int i   = tid * 16;
            const int row = i >> 9, col = i & 511;
            const size_t gi = (size_t)(r0 + c * 16 + row) * HH + col;
            const float4 n0 = *(const float4*)&noise[gi + 0];
            const float4 n1 = *(const float4*)&noise[gi + 4];
            const float4 n2 = *(const float4*)&noise[gi + 8];
            const float4 n3 = *(const float4*)&noise[gi + 12];
            const unsigned short* lp = &ls[row * 512 + col];
            const uint4 la = *(const uint4*)lp;
            const uint4 lb = *(const uint4*)(lp + 8);
            uint4 o0, o1, o2, o3;
            o0.x = ((la.x & 0xffffu) << 16) | f2bf(n0.x);
            o0.y = (la.x & 0xffff0000u)     | f2bf(n0.y);
            o0.z = ((la.y & 0xffffu) << 16) | f2bf(n0.z);
            o0.w = (la.y & 0xffff0000u)     | f2bf(n0.w);
            o1.x = ((la.z & 0xffffu) << 16) | f2bf(n1.x);
            o1.y = (la.z & 0xffff0000u)     | f2bf(n1.y);
            o1.z = ((la.w & 0xffffu) << 16) | f2bf(n1.z);
            o1.w = (la.w & 0xffff0000u)     | f2bf(n1.w);
            o2.x = ((lb.x & 0xffffu) << 16) | f2bf(n2.x);
            o2.y = (lb.x & 0xffff0000u)     | f2bf(n2.y);
            o2.z = ((lb.y & 0xffffu) << 16) | f2bf(n2.z);
            o2.w = (lb.y & 0xffff0000u)     | f2bf(n2.w);
            o3.x = ((lb.z & 0xffffu) << 16) | f2bf(n3.x);
            o3.y = (lb.z & 0xffff0000u)     | f2bf(n3.y);
            o3.z = ((lb.w & 0xffffu) << 16) | f2bf(n3.z);
            o3.w = (lb.w & 0xffff0000u)     | f2bf(n3.w);
            *(uint4*)&outp[gi + 0]  = o0;
            *(uint4*)&outp[gi + 4]  = o1;
            *(uint4*)&outp[gi + 8]  = o2;
            *(uint4*)&outp[gi + 12] = o3;
        }
        __syncthreads();
    }
}

// ---------------------------------------------------------------------------
// Kernel 3 (Design J, PROVEN rounds 12-13): j-sliced MFMA scan, LLC h-exchange.
// Round-14 edits: pk(t+1) prefetch during the exchange wait; gather remapped
// so LDS writes are lane-consecutive (kills the 4-way bank conflict).
// ---------------------------------------------------------------------------
#define WKLOAD(KC) s16x8 wk##KC = WpV[((KC) * 32 + s * 8 + w) * 64 + l]
#define WKPIN(A, B, C, D) asm volatile("" : "+v"(A), "+v"(B), "+v"(C), "+v"(D))

#define KC_EVEN(KC) do { \
    const s16x8 A = *(const s16x8*)&hrow[(KC) * 32]; \
    accA = __builtin_amdgcn_mfma_f32_16x16x32_bf16(A, wk##KC, accA, 0, 0, 0); \
} while (0)
#define KC_ODD(KC) do { \
    const s16x8 A = *(const s16x8*)&hrow[(KC) * 32]; \
    accB = __builtin_amdgcn_mfma_f32_16x16x32_bf16(A, wk##KC, accB, 0, 0, 0); \
} while (0)

__global__ __launch_bounds__(512) void scan12_kernel(const unsigned short* __restrict__ Wp,
                                                     const float* __restrict__ ah0,
                                                     unsigned int* __restrict__ hio,
                                                     unsigned short* inbox,
                                                     unsigned int* flags) {
    __shared__ __align__(16) unsigned short hs[16][520];

    const int tid = threadIdx.x;
    const int l   = tid & 63;
    const int w   = tid >> 6;
    const int lm  = l & 15;
    const int lg  = l >> 4;
    const int lg4 = lg * 4;
    const int gid = blockIdx.x;
    const int g   = gid >> 2;
    const int s   = gid & 3;
    const int b0  = g * 16;

    const s16x8* WpV = (const s16x8*)Wp;

    WKLOAD(0);  WKLOAD(1);  WKLOAD(2);  WKLOAD(3);
    WKLOAD(4);  WKLOAD(5);  WKLOAD(6);  WKLOAD(7);
    WKLOAD(8);  WKLOAD(9);  WKLOAD(10); WKLOAD(11);
    WKLOAD(12); WKLOAD(13); WKLOAD(14); WKLOAD(15);
    WKPIN(wk0, wk1, wk2, wk3);     WKPIN(wk4, wk5, wk6, wk7);
    WKPIN(wk8, wk9, wk10, wk11);   WKPIN(wk12, wk13, wk14, wk15);

    const int jn = (s * 8 + w) * 16 + lm;

    f32x4 ahv;
    {
        const float a0 = ah0[jn];
        ahv = (f32x4){a0, a0, a0, a0};
    }

    for (int idx = tid; idx < 16 * 512; idx += 512) {
        int b = idx >> 9, k = idx & 511;
        hs[b][k] = f2bf(retanh_f(ah0[k]));
    }
    __syncthreads();

    const unsigned short* hrow = &hs[lm][lg * 8];

    const int pb = tid >> 5;
    const int pq = tid & 31;
    unsigned long long* ibx = (unsigned long long*)inbox;
    const int pubIdx = (((b0 + pb) << 9) + s * 128 + pq * 4) >> 2;
    const int gatIdx = ((b0 + pb) << 7) + pq;      // u64 index of col pq*4

    int gb = (b0 + lg4) * TH + jn;

    // pk pipeline: load step-0 inputs before the loop
    unsigned int pk0 = hio[gb + 0 * TH];
    unsigned int pk1 = hio[gb + 1 * TH];
    unsigned int pk2 = hio[gb + 2 * TH];
    unsigned int pk3 = hio[gb + 3 * TH];

    for (int t = 0; t < TT; ++t) {
        const int par = (t & 1) << 16;

        f32x4 accA = (f32x4){0.f, 0.f, 0.f, 0.f};
        f32x4 accB = (f32x4){0.f, 0.f, 0.f, 0.f};
        KC_EVEN(0);  KC_ODD(1);  KC_EVEN(2);  KC_ODD(3);
        KC_EVEN(4);  KC_ODD(5);  KC_EVEN(6);  KC_ODD(7);
        KC_EVEN(8);  KC_ODD(9);  KC_EVEN(10); KC_ODD(11);
        KC_EVEN(12); KC_ODD(13); KC_EVEN(14); KC_ODD(15);
        const f32x4 acc = accA + accB;

        __syncthreads();   // BAR1: hs(t-1) reads complete

        {
            float a, h;
            unsigned int p;
            p = pk0; a = ahv[0];
            a += DT * (acc[0] + __uint_as_float(p & 0xffff0000u) - a);
            ahv[0] = a; h = retanh_f(a) + __uint_as_float(p << 16);
            hio[gb + 0 * TH] = __float_as_uint(h); hs[lg4 + 0][jn] = f2bf(h);
            p = pk1; a = ahv[1];
            a += DT * (acc[1] + __uint_as_float(p & 0xffff0000u) - a);
            ahv[1] = a; h = retanh_f(a) + __uint_as_float(p << 16);
            hio[gb + 1 * TH] = __float_as_uint(h); hs[lg4 + 1][jn] = f2bf(h);
            p = pk2; a = ahv[2];
            a += DT * (acc[2] + __uint_as_float(p & 0xffff0000u) - a);
            ahv[2] = a; h = retanh_f(a) + __uint_as_float(p << 16);
            hio[gb + 2 * TH] = __float_as_uint(h); hs[lg4 + 2][jn] = f2bf(h);
            p = pk3; a = ahv[3];
            a += DT * (acc[3] + __uint_as_float(p & 0xffff0000u) - a);
            ahv[3] = a; h = retanh_f(a) + __uint_as_float(p << 16);
            hio[gb + 3 * TH] = __float_as_uint(h); hs[lg4 + 3][jn] = f2bf(h);
        }

        __syncthreads();   // BAR2: own hs slice complete

        {
            const unsigned long long pub =
                *(const unsigned long long*)&hs[pb][s * 128 + pq * 4];
            __hip_atomic_store(&ibx[par + pubIdx], pub, __ATOMIC_RELAXED,
                               __HIP_MEMORY_SCOPE_AGENT);
        }
        asm volatile("s_waitcnt vmcnt(0)" ::: "memory");
        __syncthreads();   // BAR3: all publishes drained

        unsigned int* fl = flags + (t * NGRP + g) * NSL;
        if (tid == 0)
            __hip_atomic_store(&fl[s], 1u, __ATOMIC_RELAXED, __HIP_MEMORY_SCOPE_AGENT);

        // prefetch next step's packed inputs under the exchange wait
        if (t + 1 < TT) {
            pk0 = hio[gb + HH + 0 * TH];
            pk1 = hio[gb + HH + 1 * TH];
            pk2 = hio[gb + HH + 2 * TH];
            pk3 = hio[gb + HH + 3 * TH];
        }

        if (tid < NSL) {
            while (__hip_atomic_load(&fl[tid], __ATOMIC_RELAXED,
                                     __HIP_MEMORY_SCOPE_AGENT) == 0u)
                __builtin_amdgcn_s_sleep(1);
        }
        __syncthreads();   // BAR4: flags seen

        // gather: lane-consecutive u64s (no LDS write bank conflict)
        {
            const unsigned long long g0 = __hip_atomic_load(&ibx[par + gatIdx + 0 * 32],
                __ATOMIC_RELAXED, __HIP_MEMORY_SCOPE_AGENT);
            const unsigned long long g1 = __hip_atomic_load(&ibx[par + gatIdx + 1 * 32],
                __ATOMIC_RELAXED, __HIP_MEMORY_SCOPE_AGENT);
            const unsigned long long g2 = __hip_atomic_load(&ibx[par + gatIdx + 2 * 32],
                __ATOMIC_RELAXED, __HIP_MEMORY_SCOPE_AGENT);
            const unsigned long long g3 = __hip_atomic_load(&ibx[par + gatIdx + 3 * 32],
                __ATOMIC_RELAXED, __HIP_MEMORY_SCOPE_AGENT);
            *(unsigned long long*)&hs[pb][pq * 4 + 0 * 128] = g0;
            *(unsigned long long*)&hs[pb][pq * 4 + 1 * 128] = g1;
            *(unsigned long long*)&hs[pb][pq * 4 + 2 * 128] = g2;
            *(unsigned long long*)&hs[pb][pq * 4 + 3 * 128] = g3;
        }
        __syncthreads();   // BAR5: hs(t) complete

        gb += HH;
    }
}

// ---------------------------------------------------------------------------
// Kernel 4: tiny output projection
// ---------------------------------------------------------------------------
__global__ __launch_bounds__(256) void out_kernel(const float* __restrict__ hstore,
                                                  const float* __restrict__ Wy,
                                                  float* __restrict__ out0) {
    const int wave = threadIdx.x >> 6;
    const int lane = threadIdx.x & 63;
    const int r = blockIdx.x * 4 + wave;

    const float4* hv4 = (const float4*)&hstore[r * HH];
    float a0 = 0.0f, a1 = 0.0f;
    #pragma unroll
    for (int u = 0; u < 2; ++u) {
        const int e = u * 64 + lane;
        const float4 h  = hv4[e];
        const float4 w0 = *(const float4*)&Wy[e * 4];
        const float4 w1 = *(const float4*)&Wy[HH + e * 4];
        a0 += h.x * w0.x + h.y * w0.y + h.z * w0.z + h.w * w0.w;
        a1 += h.x * w1.x + h.y * w1.y + h.z * w1.z + h.w * w1.w;
    }
    #pragma unroll
    for (int off = 32; off > 0; off >>= 1) {
        a0 += __shfl_xor(a0, off);
        a1 += __shfl_xor(a1, off);
    }
    if (lane == 0) {
        out0[r * 2]     = a0;
        out0[r * 2 + 1] = a1;
    }
}

// ---------------------------------------------------------------------------
extern "C" void kernel_launch(void* const* d_in, const int* in_sizes, int n_in,
                              void* d_out, int out_size, void* d_ws, size_t ws_size,
                              hipStream_t stream) {
    const float* x     = (const float*)d_in[0];  // [B,T,DIN]
    const float* noise = (const float*)d_in[1];  // [B,T,H]
    const float* Wx    = (const float*)d_in[2];  // [H,DIN]
    const float* bah   = (const float*)d_in[3];  // [H]
    const float* Wh    = (const float*)d_in[4];  // [H,H]
    const float* Wy    = (const float*)d_in[5];  // [DOUT,H]
    const float* ah0   = (const float*)d_in[6];  // [H]

    float* out0   = (float*)d_out;                   // [B,T,DOUT]
    float* hstore = (float*)d_out + BB * TT * DOUTN; // [B,T,H]

    const size_t FRAG_U16 = (size_t)16 * 32 * 64 * 8;      // 512 KB
    unsigned short* Wp    = (unsigned short*)d_ws;
    unsigned short* WxH   = Wp + FRAG_U16;
    unsigned short* WxL   = WxH + FRAG_U16;
    unsigned short* inbox = WxL + FRAG_U16;                 // 1 MB (2 parities)
    unsigned int*   flags = (unsigned int*)(inbox + 2 * BB * HH);  // 128 KB

    pack_wh<<<16 * 32 * 64 / 256, 256, 0, stream>>>(Wh, Wp);
    pack_wx<<<16 * 32 * 64 / 256, 256, 0, stream>>>(Wx, WxH, WxL);
    x2ah_mfma<<<BB * TT / 128, 512, 0, stream>>>(x, WxH, WxL, Wx, bah, noise,
                                                 (unsigned int*)hstore);

    hipMemsetAsync(flags, 0, (size_t)TT * NGRP * NSL * sizeof(unsigned int), stream);
    {
        const unsigned short* wpp = Wp;
        unsigned int* hiop = (unsigned int*)hstore;
        unsigned short* ibp = inbox;
        unsigned int* flp = flags;
        void* args[] = { (void*)&wpp, (void*)&ah0, (void*)&hiop,
                         (void*)&ibp, (void*)&flp };
        hipLaunchCooperativeKernel((void*)scan12_kernel, dim3(NGRP * NSL),
                                   dim3(512), args, 0, stream);
    }

    out_kernel<<<BB * TT / 4, 256, 0, stream>>>(hstore, Wy, out0);
}